// Round 10
// baseline (302.896 us; speedup 1.0000x reference)
//
#include <hip/hip_runtime.h>
#include <hip/hip_bf16.h>
#include <math.h>

// Problem constants
#define HDIM 1024
#define TOK 2048
#define NHEAD 8
#define KD 128
#define NKEY 256
#define KSEL 8
#define BN_EPS 1e-5f

typedef _Float16 half8 __attribute__((ext_vector_type(8)));
typedef float floatx4 __attribute__((ext_vector_type(4)));

// split fp32 -> (hi f16, lo f16 scaled by 2^11), packed hi | lo<<16
__device__ __forceinline__ uint32_t pack_f16pair(float v) {
    _Float16 h = (_Float16)v;
    float hf = (float)h;
    _Float16 l = (_Float16)((v - hf) * 2048.0f);
    return (uint32_t)__builtin_bit_cast(unsigned short, h) |
           ((uint32_t)__builtin_bit_cast(unsigned short, l) << 16);
}

// ---------------- K1: BatchNorm partial sums ----------------
__global__ __launch_bounds__(256) void bn_partial_k(const float* __restrict__ x,
                                                    float* __restrict__ psum,
                                                    float* __restrict__ psq) {
    int b = blockIdx.x;
    int t = threadIdx.x;
    float s[4] = {0.f, 0.f, 0.f, 0.f};
    float s2[4] = {0.f, 0.f, 0.f, 0.f};
    int r0 = b * 32;
    for (int r = 0; r < 32; ++r) {
        const float* row = x + (size_t)(r0 + r) * HDIM;
#pragma unroll
        for (int j = 0; j < 4; ++j) {
            float v = row[t + j * 256];
            s[j] += v;
            s2[j] += v * v;
        }
    }
#pragma unroll
    for (int j = 0; j < 4; ++j) {
        psum[b * HDIM + t + j * 256] = s[j];
        psq[b * HDIM + t + j * 256] = s2[j];
    }
}

// ---------------- K2: finalize scale/shift ----------------
__global__ __launch_bounds__(256) void bn_final_k(const float* __restrict__ psum,
                                                  const float* __restrict__ psq,
                                                  const float* __restrict__ gamma,
                                                  const float* __restrict__ beta,
                                                  float* __restrict__ scale,
                                                  float* __restrict__ shift) {
    int c = blockIdx.x * 256 + threadIdx.x;
    float s = 0.f, s2 = 0.f;
    for (int b = 0; b < 64; ++b) {
        s += psum[b * HDIM + c];
        s2 += psq[b * HDIM + c];
    }
    float mean = s * (1.0f / TOK);
    float var = s2 * (1.0f / TOK) - mean * mean;
    float sc = gamma[c] * rsqrtf(var + BN_EPS);
    scale[c] = sc;
    shift[c] = beta[c] - mean * sc;
}

// ---------------- MFMA GEMM with fused fp32->f16-split staging ----------------
// 512 threads = 8 waves (2m x 4n), tile 128x128, BK=32, single LDS buffer,
// global prefetch overlapped with MFMA.
// MODE 0: A = x fp32 (BN scale/shift fused on stage), B = w_q fp32.
//         grid (16,16,1), K=1024. C -> packed u32 qpk.
// MODE 1: A = qpk packed u32, B = keys fp32 raw [h][256][2][128].
//         grid (16,2,16), z=(p,h), K=128. C -> fp32 sim (ldc 4096).
template <int MODE>
__global__ __launch_bounds__(512) void mgemm_k(const float* __restrict__ Af,
                                               const uint32_t* __restrict__ Apk,
                                               const float* __restrict__ Bf,
                                               float* __restrict__ Cf,
                                               uint32_t* __restrict__ Cp,
                                               const float* __restrict__ scale,
                                               const float* __restrict__ shift) {
    __shared__ _Float16 Ah[128][40];
    __shared__ _Float16 Al[128][40];
    __shared__ _Float16 Bh[128][40];
    __shared__ _Float16 Bl[128][40];

    const int tid = threadIdx.x;
    const int m0 = blockIdx.x * 128;
    const int n0 = blockIdx.y * 128;

    // staging role: threads 0..255 stage A rows m0..m0+127; 256..511 stage B rows n0..n0+127
    const int st = tid & 255;
    const int srow = st >> 1;
    const int skh = (st & 1) * 16;     // k-half within the 32-wide step
    const bool isB = (tid >= 256);

    int NS;
    const float* spf = nullptr;        // fp32 staging source
    const uint32_t* spp = nullptr;     // packed staging source
    size_t cbase = 0;
    if (MODE == 0) {
        NS = 32;
        spf = (isB ? (Bf + (size_t)(n0 + srow) * 1024)
                   : (Af + (size_t)(m0 + srow) * 1024)) + skh;
    } else {
        NS = 4;
        int z = blockIdx.z, p = z >> 3, h = z & 7;
        if (isB) spf = Bf + (size_t)h * 65536 + (size_t)(n0 + srow) * 256 + p * 128 + skh;
        else     spp = Apk + (size_t)(m0 + srow) * 2048 + p * 1024 + h * 128 + skh;
        cbase = (size_t)(p * 2048 + h * 256);
    }

    _Float16* Hp = isB ? &Bh[srow][skh] : &Ah[srow][skh];
    _Float16* Lp = isB ? &Bl[srow][skh] : &Al[srow][skh];

    const int w = tid >> 6, lane = tid & 63;
    const int wm = w >> 2, wn = w & 3;          // wave sub-tile 64(m) x 32(n)
    const int fr = lane & 15, kg = lane >> 4;   // frag row, k-group

    floatx4 acc1[4][2];  // hi*hi
    floatx4 acc2[4][2];  // cross terms (scaled by 2^11)
#pragma unroll
    for (int i = 0; i < 4; ++i)
#pragma unroll
        for (int j = 0; j < 2; ++j) {
            acc1[i][j] = (floatx4)0.0f;
            acc2[i][j] = (floatx4)0.0f;
        }

    float rf[16];
    uint32_t rp[16];

    auto gload = [&](int s) {
        if (MODE == 1 && !isB) {
            const uint32_t* p = spp + s * 32;
#pragma unroll
            for (int j = 0; j < 4; ++j) *(uint4*)&rp[j * 4] = *(const uint4*)(p + j * 4);
        } else {
            const float* p = spf + s * 32;
#pragma unroll
            for (int j = 0; j < 4; ++j) *(float4*)&rf[j * 4] = *(const float4*)(p + j * 4);
        }
    };
    auto lwrite = [&](int s) {
        __align__(16) _Float16 hh[16], ll[16];
        if (MODE == 1 && !isB) {
            // packed u32 -> hi/lo halves via byte-perm
#pragma unroll
            for (int j = 0; j < 8; ++j) {
                uint32_t hw = __builtin_amdgcn_perm(rp[2 * j + 1], rp[2 * j], 0x05040100u);
                uint32_t lw = __builtin_amdgcn_perm(rp[2 * j + 1], rp[2 * j], 0x07060302u);
                *(uint32_t*)&hh[2 * j] = hw;
                *(uint32_t*)&ll[2 * j] = lw;
            }
        } else {
            float sv[16], hv[16];
            if (MODE == 0 && !isB) {
                const int c0 = s * 32 + skh;
#pragma unroll
                for (int jj = 0; jj < 4; ++jj) {
                    *(float4*)&sv[jj * 4] = *(const float4*)(scale + c0 + jj * 4);
                    *(float4*)&hv[jj * 4] = *(const float4*)(shift + c0 + jj * 4);
                }
            }
#pragma unroll
            for (int j = 0; j < 16; ++j) {
                float v = rf[j];
                if (MODE == 0 && !isB) v = fmaf(v, sv[j], hv[j]);
                _Float16 h = (_Float16)v;
                hh[j] = h;
                ll[j] = (_Float16)((v - (float)h) * 2048.0f);
            }
        }
        *(uint4*)(Hp) = *(uint4*)&hh[0];
        *(uint4*)(Hp + 8) = *(uint4*)&hh[8];
        *(uint4*)(Lp) = *(uint4*)&ll[0];
        *(uint4*)(Lp + 8) = *(uint4*)&ll[8];
    };

    gload(0);
    lwrite(0);
    for (int s = 0; s < NS; ++s) {
        if (s + 1 < NS) gload(s + 1);     // issue next-tile global loads early
        __syncthreads();                  // tile s LDS writes visible
        half8 ah[4], al[4], bh2[2], bl2[2];
#pragma unroll
        for (int mf = 0; mf < 4; ++mf) {
            int r = wm * 64 + mf * 16 + fr;
            ah[mf] = *(const half8*)&Ah[r][kg * 8];
            al[mf] = *(const half8*)&Al[r][kg * 8];
        }
#pragma unroll
        for (int nf = 0; nf < 2; ++nf) {
            int r = wn * 32 + nf * 16 + fr;
            bh2[nf] = *(const half8*)&Bh[r][kg * 8];
            bl2[nf] = *(const half8*)&Bl[r][kg * 8];
        }
#pragma unroll
        for (int mf = 0; mf < 4; ++mf)
#pragma unroll
            for (int nf = 0; nf < 2; ++nf) {
                acc1[mf][nf] = __builtin_amdgcn_mfma_f32_16x16x32_f16(ah[mf], bh2[nf], acc1[mf][nf], 0, 0, 0);
                acc2[mf][nf] = __builtin_amdgcn_mfma_f32_16x16x32_f16(ah[mf], bl2[nf], acc2[mf][nf], 0, 0, 0);
                acc2[mf][nf] = __builtin_amdgcn_mfma_f32_16x16x32_f16(al[mf], bh2[nf], acc2[mf][nf], 0, 0, 0);
            }
        __syncthreads();                  // all reads of tile s done
        if (s + 1 < NS) lwrite(s + 1);
    }

    // epilogue: C/D layout col=lane&15, row=(lane>>4)*4+reg
#pragma unroll
    for (int mf = 0; mf < 4; ++mf)
#pragma unroll
        for (int nf = 0; nf < 2; ++nf)
#pragma unroll
            for (int r = 0; r < 4; ++r) {
                float q = acc1[mf][nf][r] + acc2[mf][nf][r] * (1.0f / 2048.0f);
                int row = m0 + wm * 64 + mf * 16 + kg * 4 + r;
                int col = n0 + wn * 32 + nf * 16 + fr;
                if (MODE == 0)
                    Cp[(size_t)row * 2048 + col] = pack_f16pair(q);
                else
                    Cf[cbase + (size_t)row * 4096 + col] = q;
            }
}

// ---------------- K4: top-k per (token, head) ----------------
__global__ __launch_bounds__(512) void topk_k(const float* __restrict__ sim,
                                              int* __restrict__ eidx,
                                              float* __restrict__ gates) {
    int t = blockIdx.x;
    int h = threadIdx.x >> 6;
    int lane = threadIdx.x & 63;
    const float* s0p = sim + (size_t)t * 4096 + h * 256;
    const float* s1p = s0p + 2048;
    float4 v0 = *(const float4*)(s0p + lane * 4);
    float4 v1 = *(const float4*)(s1p + lane * 4);
    float c0[4] = {v0.x, v0.y, v0.z, v0.w};
    float c1[4] = {v1.x, v1.y, v1.z, v1.w};

    float tv0[8], tv1[8];
    int ti0[8], ti1[8];

#pragma unroll
    for (int r = 0; r < 8; ++r) {
        float bv = c0[0];
        int bi = lane * 4;
#pragma unroll
        for (int j = 1; j < 4; ++j)
            if (c0[j] > bv) { bv = c0[j]; bi = lane * 4 + j; }
#pragma unroll
        for (int off = 1; off < 64; off <<= 1) {
            float ov = __shfl_xor(bv, off);
            int oi = __shfl_xor(bi, off);
            if (ov > bv || (ov == bv && oi < bi)) { bv = ov; bi = oi; }
        }
        tv0[r] = bv;
        ti0[r] = bi;
        if ((bi >> 2) == lane) {
            int jj = bi & 3;
#pragma unroll
            for (int q = 0; q < 4; ++q)
                if (q == jj) c0[q] = -INFINITY;
        }
    }
#pragma unroll
    for (int r = 0; r < 8; ++r) {
        float bv = c1[0];
        int bi = lane * 4;
#pragma unroll
        for (int j = 1; j < 4; ++j)
            if (c1[j] > bv) { bv = c1[j]; bi = lane * 4 + j; }
#pragma unroll
        for (int off = 1; off < 64; off <<= 1) {
            float ov = __shfl_xor(bv, off);
            int oi = __shfl_xor(bi, off);
            if (ov > bv || (ov == bv && oi < bi)) { bv = ov; bi = oi; }
        }
        tv1[r] = bv;
        ti1[r] = bi;
        if ((bi >> 2) == lane) {
            int jj = bi & 3;
#pragma unroll
            for (int q = 0; q < 4; ++q)
                if (q == jj) c1[q] = -INFINITY;
        }
    }

    int ii = lane >> 3, jj = lane & 7;
    float a = -INFINITY, b = -INFINITY;
#pragma unroll
    for (int r = 0; r < 8; ++r) {
        if (ii == r) a = tv0[r];
        if (jj == r) b = tv1[r];
    }
    float cv = a + b;
    int cpos = lane;

    int outbase = (t * NHEAD + h) * KSEL;
#pragma unroll
    for (int r = 0; r < 8; ++r) {
        float bv = cv;
        int bp = cpos;
#pragma unroll
        for (int off = 1; off < 64; off <<= 1) {
            float ov = __shfl_xor(bv, off);
            int op = __shfl_xor(bp, off);
            if (ov > bv || (ov == bv && op < bp)) { bv = ov; bp = op; }
        }
        if (lane == 0) {
            int pi = bp >> 3, pj = bp & 7;
            int e0 = 0, e1 = 0;
#pragma unroll
            for (int q = 0; q < 8; ++q) {
                if (pi == q) e0 = ti0[q];
                if (pj == q) e1 = ti1[q];
            }
            eidx[outbase + r] = e0 * NKEY + e1;
            gates[outbase + r] = 1.0f / (1.0f + expf(-bv));
        }
        if (lane == bp) cv = -INFINITY;
    }
}

// ---------------- K5: expert gather + compute (at pattern ceiling) ----------------
__global__ __launch_bounds__(512, 2) void expert_k(const float* __restrict__ x,
                                                   const float* __restrict__ down,
                                                   const float* __restrict__ up,
                                                   const int* __restrict__ eidx,
                                                   const float* __restrict__ gates,
                                                   float* __restrict__ out) {
    int t = blockIdx.x;
    int w = threadIdx.x >> 6;
    int lane = threadIdx.x & 63;
    __shared__ __align__(16) float4 accs[8][256];

    const float4* x4 = (const float4*)(x + (size_t)t * HDIM);
    float4 xv[4];
#pragma unroll
    for (int j = 0; j < 4; ++j) xv[j] = x4[lane + 64 * j];

    int base = t * 64 + w * 8;
    int e[8];
    float g[8];
#pragma unroll
    for (int i = 0; i < 8; ++i) {
        e[i] = eidx[base + i];
        g[i] = gates[base + i];
    }

    float dot[8];
#pragma unroll
    for (int i = 0; i < 8; ++i) dot[i] = 0.f;
#pragma unroll
    for (int i = 0; i < 8; ++i) {
        const float4* d = (const float4*)(down + (size_t)e[i] * HDIM);
#pragma unroll
        for (int j = 0; j < 4; ++j) {
            float4 dv = d[lane + 64 * j];
            dot[i] += xv[j].x * dv.x + xv[j].y * dv.y + xv[j].z * dv.z + xv[j].w * dv.w;
        }
    }

#pragma unroll
    for (int off = 32; off >= 1; off >>= 1) {
#pragma unroll
        for (int i = 0; i < 8; ++i) dot[i] += __shfl_xor(dot[i], off);
    }
    float hm[8];
#pragma unroll
    for (int i = 0; i < 8; ++i) {
        float d = dot[i];
        hm[i] = g[i] * 0.5f * d * (1.0f + erff(d * 0.70710678118654752f));
    }

    float4 acc[4];
#pragma unroll
    for (int j = 0; j < 4; ++j) acc[j] = make_float4(0.f, 0.f, 0.f, 0.f);
#pragma unroll
    for (int i = 0; i < 8; ++i) {
        const float4* u = (const float4*)(up + (size_t)e[i] * HDIM);
        float h = hm[i];
#pragma unroll
        for (int j = 0; j < 4; ++j) {
            float4 uv = u[lane + 64 * j];
            acc[j].x = fmaf(h, uv.x, acc[j].x);
            acc[j].y = fmaf(h, uv.y, acc[j].y);
            acc[j].z = fmaf(h, uv.z, acc[j].z);
            acc[j].w = fmaf(h, uv.w, acc[j].w);
        }
    }

#pragma unroll
    for (int j = 0; j < 4; ++j) accs[w][lane + 64 * j] = acc[j];
    __syncthreads();
    if (threadIdx.x < 256) {
        int s = threadIdx.x;
        float4 o = accs[0][s];
#pragma unroll
        for (int ww = 1; ww < 8; ++ww) {
            float4 r = accs[ww][s];
            o.x += r.x; o.y += r.y; o.z += r.z; o.w += r.w;
        }
        ((float4*)(out + (size_t)t * HDIM))[s] = o;
    }
}

// ---------------- launch ----------------
extern "C" void kernel_launch(void* const* d_in, const int* in_sizes, int n_in,
                              void* d_out, int out_size, void* d_ws, size_t ws_size,
                              hipStream_t stream) {
    const float* x = (const float*)d_in[0];
    const float* gamma = (const float*)d_in[1];
    const float* beta = (const float*)d_in[2];
    const float* w_q = (const float*)d_in[3];
    const float* keys = (const float*)d_in[4];
    const float* down = (const float*)d_in[5];
    const float* up = (const float*)d_in[6];
    float* out = (float*)d_out;
    float* ws = (float*)d_ws;

    // ws layout (float offsets), total 13107200 floats = 52.4 MB
    float* psum = ws;                          // 0 .. 65536
    float* psq = ws + 65536;                   // .. 131072
    float* scale = ws + 131072;                // 1024
    float* shift = ws + 132096;                // 1024
    int* eidx = (int*)(ws + 133120);           // .. 264192
    float* gates = ws + 264192;                // .. 395264
    uint32_t* qpk = (uint32_t*)(ws + 524288);  // 2048x2048 u32  .. 4718592
    float* sim = ws + 4718592;                 // 2048x4096 f32  .. 13107200

    bn_partial_k<<<64, 256, 0, stream>>>(x, psum, psq);
    bn_final_k<<<4, 256, 0, stream>>>(psum, psq, gamma, beta, scale, shift);

    // q = (x*scale+shift) @ w_q^T, split+packed output
    mgemm_k<0><<<dim3(16, 16, 1), 512, 0, stream>>>(x, nullptr, w_q, nullptr, qpk,
                                                    scale, shift);
    // sim = q @ keys^T per (p,h), keys staged raw fp32
    mgemm_k<1><<<dim3(16, 2, 16), 512, 0, stream>>>(nullptr, qpk, keys, sim, nullptr,
                                                    nullptr, nullptr);

    topk_k<<<2048, 512, 0, stream>>>(sim, eidx, gates);
    expert_k<<<2048, 512, 0, stream>>>(x, down, up, eidx, gates, out);
}

// Round 11
// 281.925 us; speedup vs baseline: 1.0744x; 1.0744x over previous
//
#include <hip/hip_runtime.h>
#include <hip/hip_bf16.h>
#include <math.h>

// Problem constants
#define HDIM 1024
#define TOK 2048
#define NHEAD 8
#define KD 128
#define NKEY 256
#define KSEL 8
#define BN_EPS 1e-5f

typedef _Float16 half8 __attribute__((ext_vector_type(8)));
typedef float floatx4 __attribute__((ext_vector_type(4)));

// split fp32 -> (hi f16, lo f16 scaled by 2^11), packed hi | lo<<16
__device__ __forceinline__ uint32_t pack_f16pair(float v) {
    _Float16 h = (_Float16)v;
    float hf = (float)h;
    _Float16 l = (_Float16)((v - hf) * 2048.0f);
    return (uint32_t)__builtin_bit_cast(unsigned short, h) |
           ((uint32_t)__builtin_bit_cast(unsigned short, l) << 16);
}

// ---------------- K1: BatchNorm partial sums ----------------
__global__ __launch_bounds__(256) void bn_partial_k(const float* __restrict__ x,
                                                    float* __restrict__ psum,
                                                    float* __restrict__ psq) {
    int b = blockIdx.x;
    int t = threadIdx.x;
    float s[4] = {0.f, 0.f, 0.f, 0.f};
    float s2[4] = {0.f, 0.f, 0.f, 0.f};
    int r0 = b * 32;
    for (int r = 0; r < 32; ++r) {
        const float* row = x + (size_t)(r0 + r) * HDIM;
#pragma unroll
        for (int j = 0; j < 4; ++j) {
            float v = row[t + j * 256];
            s[j] += v;
            s2[j] += v * v;
        }
    }
#pragma unroll
    for (int j = 0; j < 4; ++j) {
        psum[b * HDIM + t + j * 256] = s[j];
        psq[b * HDIM + t + j * 256] = s2[j];
    }
}

// ---------------- K2: finalize scale/shift ----------------
__global__ __launch_bounds__(256) void bn_final_k(const float* __restrict__ psum,
                                                  const float* __restrict__ psq,
                                                  const float* __restrict__ gamma,
                                                  const float* __restrict__ beta,
                                                  float* __restrict__ scale,
                                                  float* __restrict__ shift) {
    int c = blockIdx.x * 256 + threadIdx.x;
    float s = 0.f, s2 = 0.f;
    for (int b = 0; b < 64; ++b) {
        s += psum[b * HDIM + c];
        s2 += psq[b * HDIM + c];
    }
    float mean = s * (1.0f / TOK);
    float var = s2 * (1.0f / TOK) - mean * mean;
    float sc = gamma[c] * rsqrtf(var + BN_EPS);
    scale[c] = sc;
    shift[c] = beta[c] - mean * sc;
}

// ---------------- cvt (merged): x-norm | w_q | keys -> packed f16-pair ----------
// grid 4608: blocks 0..2047 x (normalized), 2048..4095 w_q, 4096..4607 keys.
__global__ __launch_bounds__(256) void cvt_all_k(const float* __restrict__ x,
                                                 const float* __restrict__ wq,
                                                 const float* __restrict__ keys,
                                                 uint32_t* __restrict__ xpk,
                                                 uint32_t* __restrict__ wpk,
                                                 uint32_t* __restrict__ kpk,
                                                 const float* __restrict__ sc,
                                                 const float* __restrict__ sh) {
    int b = blockIdx.x;
    if (b < 2048) {
        int i = (b * 256 + threadIdx.x) * 4;
        float4 v = *(const float4*)(x + i);
        int c = i & 1023;
        float4 s4 = *(const float4*)(sc + c);
        float4 h4 = *(const float4*)(sh + c);
        v.x = fmaf(v.x, s4.x, h4.x);
        v.y = fmaf(v.y, s4.y, h4.y);
        v.z = fmaf(v.z, s4.z, h4.z);
        v.w = fmaf(v.w, s4.w, h4.w);
        uint4 o;
        o.x = pack_f16pair(v.x);
        o.y = pack_f16pair(v.y);
        o.z = pack_f16pair(v.z);
        o.w = pack_f16pair(v.w);
        *(uint4*)(xpk + i) = o;
    } else if (b < 4096) {
        int i = ((b - 2048) * 256 + threadIdx.x) * 4;
        float4 v = *(const float4*)(wq + i);
        uint4 o;
        o.x = pack_f16pair(v.x);
        o.y = pack_f16pair(v.y);
        o.z = pack_f16pair(v.z);
        o.w = pack_f16pair(v.w);
        *(uint4*)(wpk + i) = o;
    } else {
        // keys [h][nk][p][d] -> kpk [(h*2+p)][nk][d], 4 elems/thread
        int i = ((b - 4096) * 256 + threadIdx.x) * 4;   // 0..524284
        int d = i & 127;
        int nk = (i >> 7) & 255;
        int hp = i >> 15;
        int h = hp >> 1, p = hp & 1;
        float4 v = *(const float4*)(keys + h * 65536 + nk * 256 + p * 128 + d);
        uint4 o;
        o.x = pack_f16pair(v.x);
        o.y = pack_f16pair(v.y);
        o.z = pack_f16pair(v.z);
        o.w = pack_f16pair(v.w);
        *(uint4*)(kpk + i) = o;
    }
}

// ---------------- MFMA GEMM: C = A * B^T via 3-term f16 split (R9-proven) --------
// A, B packed u32 (hi|lo f16). 512 threads = 8 waves (2m x 4n), tile 128x128, BK=32.
// MODE 0: q GEMM  M=N=2048 K=1024, grid (16,16,1), C -> packed u32 qpk (ldc 2048)
// MODE 1: sim GEMM per z=(p,h): K=128, grid (16,2,16), C -> fp32 sim (ldc 4096)
template <int MODE>
__global__ __launch_bounds__(512) void mgemm_k(const uint32_t* __restrict__ A,
                                               const uint32_t* __restrict__ B,
                                               float* __restrict__ Cf,
                                               uint32_t* __restrict__ Cp) {
    __shared__ _Float16 Ah[128][40];
    __shared__ _Float16 Al[128][40];
    __shared__ _Float16 Bh[128][40];
    __shared__ _Float16 Bl[128][40];

    const int tid = threadIdx.x;
    const int m0 = blockIdx.x * 128;
    const int n0 = blockIdx.y * 128;

    const uint32_t* Ab;
    const uint32_t* Bb;
    int lda, ldb, NS, ldc;
    size_t cbase;
    if (MODE == 0) {
        lda = 1024; ldb = 1024; NS = 32; ldc = 2048; cbase = 0;
        Ab = A; Bb = B;
    } else {
        lda = 2048; ldb = 128; NS = 4; ldc = 4096;
        int z = blockIdx.z, p = z >> 3, h = z & 7;
        Ab = A + p * 1024 + h * 128;
        Bb = B + (size_t)(h * 2 + p) * 32768;
        cbase = p * 2048 + h * 256;
    }

    // staging: waves 0-3 stage A (block rows m0..m0+127), waves 4-7 stage B (n0..n0+127)
    const int st = tid & 255;
    const int srow = st >> 1;
    const int skh = (st & 1) * 16;
    const bool isB = (tid >= 256);
    const uint32_t* sp = (isB ? (Bb + (size_t)(n0 + srow) * ldb)
                              : (Ab + (size_t)(m0 + srow) * lda)) + skh;
    _Float16* Hp = isB ? &Bh[srow][skh] : &Ah[srow][skh];
    _Float16* Lp = isB ? &Bl[srow][skh] : &Al[srow][skh];

    const int w = tid >> 6, lane = tid & 63;
    const int wm = w >> 2, wn = w & 3;          // wave sub-tile 64(m) x 32(n)
    const int fr = lane & 15, kg = lane >> 4;   // frag row, k-group

    floatx4 acc1[4][2];  // hi*hi
    floatx4 acc2[4][2];  // cross terms (scaled by 2^11)
#pragma unroll
    for (int i = 0; i < 4; ++i)
#pragma unroll
        for (int j = 0; j < 2; ++j) {
            acc1[i][j] = (floatx4)0.0f;
            acc2[i][j] = (floatx4)0.0f;
        }

    uint32_t rg[16];
    auto gload = [&](int s) {
        const uint32_t* p = sp + s * 32;
#pragma unroll
        for (int j = 0; j < 4; ++j) *(uint4*)&rg[j * 4] = *(const uint4*)(p + j * 4);
    };
    auto lwrite = [&]() {
        uint32_t hh[8], ll[8];
#pragma unroll
        for (int j = 0; j < 8; ++j) {
            hh[j] = __builtin_amdgcn_perm(rg[2 * j + 1], rg[2 * j], 0x05040100u);
            ll[j] = __builtin_amdgcn_perm(rg[2 * j + 1], rg[2 * j], 0x07060302u);
        }
        *(uint4*)(Hp) = *(uint4*)&hh[0];
        *(uint4*)(Hp + 8) = *(uint4*)&hh[4];
        *(uint4*)(Lp) = *(uint4*)&ll[0];
        *(uint4*)(Lp + 8) = *(uint4*)&ll[4];
    };

    gload(0);
    lwrite();
    for (int s = 0; s < NS; ++s) {
        if (s + 1 < NS) gload(s + 1);     // issue next-tile global loads early
        __syncthreads();                  // tile s LDS writes visible
        half8 ah[4], al[4], bh2[2], bl2[2];
#pragma unroll
        for (int mf = 0; mf < 4; ++mf) {
            int r = wm * 64 + mf * 16 + fr;
            ah[mf] = *(const half8*)&Ah[r][kg * 8];
            al[mf] = *(const half8*)&Al[r][kg * 8];
        }
#pragma unroll
        for (int nf = 0; nf < 2; ++nf) {
            int r = wn * 32 + nf * 16 + fr;
            bh2[nf] = *(const half8*)&Bh[r][kg * 8];
            bl2[nf] = *(const half8*)&Bl[r][kg * 8];
        }
#pragma unroll
        for (int mf = 0; mf < 4; ++mf)
#pragma unroll
            for (int nf = 0; nf < 2; ++nf) {
                acc1[mf][nf] = __builtin_amdgcn_mfma_f32_16x16x32_f16(ah[mf], bh2[nf], acc1[mf][nf], 0, 0, 0);
                acc2[mf][nf] = __builtin_amdgcn_mfma_f32_16x16x32_f16(ah[mf], bl2[nf], acc2[mf][nf], 0, 0, 0);
                acc2[mf][nf] = __builtin_amdgcn_mfma_f32_16x16x32_f16(al[mf], bh2[nf], acc2[mf][nf], 0, 0, 0);
            }
        __syncthreads();                  // all reads of tile s done
        if (s + 1 < NS) lwrite();
    }

    // epilogue: C/D layout col=lane&15, row=(lane>>4)*4+reg
#pragma unroll
    for (int mf = 0; mf < 4; ++mf)
#pragma unroll
        for (int nf = 0; nf < 2; ++nf)
#pragma unroll
            for (int r = 0; r < 4; ++r) {
                float q = acc1[mf][nf][r] + acc2[mf][nf][r] * (1.0f / 2048.0f);
                int row = m0 + wm * 64 + mf * 16 + kg * 4 + r;
                int col = n0 + wn * 32 + nf * 16 + fr;
                if (MODE == 0)
                    Cp[(size_t)row * 2048 + col] = pack_f16pair(q);
                else
                    Cf[cbase + (size_t)row * (size_t)ldc + col] = q;
            }
}

// ---------------- K4: top-k per (token, head) ----------------
__global__ __launch_bounds__(512) void topk_k(const float* __restrict__ sim,
                                              int* __restrict__ eidx,
                                              float* __restrict__ gates) {
    int t = blockIdx.x;
    int h = threadIdx.x >> 6;
    int lane = threadIdx.x & 63;
    const float* s0p = sim + (size_t)t * 4096 + h * 256;
    const float* s1p = s0p + 2048;
    float4 v0 = *(const float4*)(s0p + lane * 4);
    float4 v1 = *(const float4*)(s1p + lane * 4);
    float c0[4] = {v0.x, v0.y, v0.z, v0.w};
    float c1[4] = {v1.x, v1.y, v1.z, v1.w};

    float tv0[8], tv1[8];
    int ti0[8], ti1[8];

#pragma unroll
    for (int r = 0; r < 8; ++r) {
        float bv = c0[0];
        int bi = lane * 4;
#pragma unroll
        for (int j = 1; j < 4; ++j)
            if (c0[j] > bv) { bv = c0[j]; bi = lane * 4 + j; }
#pragma unroll
        for (int off = 1; off < 64; off <<= 1) {
            float ov = __shfl_xor(bv, off);
            int oi = __shfl_xor(bi, off);
            if (ov > bv || (ov == bv && oi < bi)) { bv = ov; bi = oi; }
        }
        tv0[r] = bv;
        ti0[r] = bi;
        if ((bi >> 2) == lane) {
            int jj = bi & 3;
#pragma unroll
            for (int q = 0; q < 4; ++q)
                if (q == jj) c0[q] = -INFINITY;
        }
    }
#pragma unroll
    for (int r = 0; r < 8; ++r) {
        float bv = c1[0];
        int bi = lane * 4;
#pragma unroll
        for (int j = 1; j < 4; ++j)
            if (c1[j] > bv) { bv = c1[j]; bi = lane * 4 + j; }
#pragma unroll
        for (int off = 1; off < 64; off <<= 1) {
            float ov = __shfl_xor(bv, off);
            int oi = __shfl_xor(bi, off);
            if (ov > bv || (ov == bv && oi < bi)) { bv = ov; bi = oi; }
        }
        tv1[r] = bv;
        ti1[r] = bi;
        if ((bi >> 2) == lane) {
            int jj = bi & 3;
#pragma unroll
            for (int q = 0; q < 4; ++q)
                if (q == jj) c1[q] = -INFINITY;
        }
    }

    int ii = lane >> 3, jj = lane & 7;
    float a = -INFINITY, b = -INFINITY;
#pragma unroll
    for (int r = 0; r < 8; ++r) {
        if (ii == r) a = tv0[r];
        if (jj == r) b = tv1[r];
    }
    float cv = a + b;
    int cpos = lane;

    int outbase = (t * NHEAD + h) * KSEL;
#pragma unroll
    for (int r = 0; r < 8; ++r) {
        float bv = cv;
        int bp = cpos;
#pragma unroll
        for (int off = 1; off < 64; off <<= 1) {
            float ov = __shfl_xor(bv, off);
            int op = __shfl_xor(bp, off);
            if (ov > bv || (ov == bv && op < bp)) { bv = ov; bp = op; }
        }
        if (lane == 0) {
            int pi = bp >> 3, pj = bp & 7;
            int e0 = 0, e1 = 0;
#pragma unroll
            for (int q = 0; q < 8; ++q) {
                if (pi == q) e0 = ti0[q];
                if (pj == q) e1 = ti1[q];
            }
            eidx[outbase + r] = e0 * NKEY + e1;
            gates[outbase + r] = 1.0f / (1.0f + expf(-bv));
        }
        if (lane == bp) cv = -INFINITY;
    }
}

// ---------------- K5: expert gather + compute (at pattern ceiling) ----------------
__global__ __launch_bounds__(512, 2) void expert_k(const float* __restrict__ x,
                                                   const float* __restrict__ down,
                                                   const float* __restrict__ up,
                                                   const int* __restrict__ eidx,
                                                   const float* __restrict__ gates,
                                                   float* __restrict__ out) {
    int t = blockIdx.x;
    int w = threadIdx.x >> 6;
    int lane = threadIdx.x & 63;
    __shared__ __align__(16) float4 accs[8][256];

    const float4* x4 = (const float4*)(x + (size_t)t * HDIM);
    float4 xv[4];
#pragma unroll
    for (int j = 0; j < 4; ++j) xv[j] = x4[lane + 64 * j];

    int base = t * 64 + w * 8;
    int e[8];
    float g[8];
#pragma unroll
    for (int i = 0; i < 8; ++i) {
        e[i] = eidx[base + i];
        g[i] = gates[base + i];
    }

    float dot[8];
#pragma unroll
    for (int i = 0; i < 8; ++i) dot[i] = 0.f;
#pragma unroll
    for (int i = 0; i < 8; ++i) {
        const float4* d = (const float4*)(down + (size_t)e[i] * HDIM);
#pragma unroll
        for (int j = 0; j < 4; ++j) {
            float4 dv = d[lane + 64 * j];
            dot[i] += xv[j].x * dv.x + xv[j].y * dv.y + xv[j].z * dv.z + xv[j].w * dv.w;
        }
    }

#pragma unroll
    for (int off = 32; off >= 1; off >>= 1) {
#pragma unroll
        for (int i = 0; i < 8; ++i) dot[i] += __shfl_xor(dot[i], off);
    }
    float hm[8];
#pragma unroll
    for (int i = 0; i < 8; ++i) {
        float d = dot[i];
        hm[i] = g[i] * 0.5f * d * (1.0f + erff(d * 0.70710678118654752f));
    }

    float4 acc[4];
#pragma unroll
    for (int j = 0; j < 4; ++j) acc[j] = make_float4(0.f, 0.f, 0.f, 0.f);
#pragma unroll
    for (int i = 0; i < 8; ++i) {
        const float4* u = (const float4*)(up + (size_t)e[i] * HDIM);
        float h = hm[i];
#pragma unroll
        for (int j = 0; j < 4; ++j) {
            float4 uv = u[lane + 64 * j];
            acc[j].x = fmaf(h, uv.x, acc[j].x);
            acc[j].y = fmaf(h, uv.y, acc[j].y);
            acc[j].z = fmaf(h, uv.z, acc[j].z);
            acc[j].w = fmaf(h, uv.w, acc[j].w);
        }
    }

#pragma unroll
    for (int j = 0; j < 4; ++j) accs[w][lane + 64 * j] = acc[j];
    __syncthreads();
    if (threadIdx.x < 256) {
        int s = threadIdx.x;
        float4 o = accs[0][s];
#pragma unroll
        for (int ww = 1; ww < 8; ++ww) {
            float4 r = accs[ww][s];
            o.x += r.x; o.y += r.y; o.z += r.z; o.w += r.w;
        }
        ((float4*)(out + (size_t)t * HDIM))[s] = o;
    }
}

// ---------------- launch ----------------
extern "C" void kernel_launch(void* const* d_in, const int* in_sizes, int n_in,
                              void* d_out, int out_size, void* d_ws, size_t ws_size,
                              hipStream_t stream) {
    const float* x = (const float*)d_in[0];
    const float* gamma = (const float*)d_in[1];
    const float* beta = (const float*)d_in[2];
    const float* w_q = (const float*)d_in[3];
    const float* keys = (const float*)d_in[4];
    const float* down = (const float*)d_in[5];
    const float* up = (const float*)d_in[6];
    float* out = (float*)d_out;
    float* ws = (float*)d_ws;

    // ws layout (float offsets), total 13631488 floats = 54.5 MB
    float* psum = ws;                          // 0 .. 65536
    float* psq = ws + 65536;                   // .. 131072
    float* scale = ws + 131072;                // 1024
    float* shift = ws + 132096;                // 1024
    int* eidx = (int*)(ws + 133120);           // .. 264192
    float* gates = ws + 264192;                // .. 395264
    uint32_t* xpk = (uint32_t*)(ws + 524288);  // 2048x1024 u32   (dead after gemm0)
    uint32_t* wpk = (uint32_t*)(ws + 2621440); // 2048x1024 u32   (dead after gemm0)
    float* sim = ws + 524288;                  // 2048x4096 f32, OVERLAYS xpk+wpk
    uint32_t* kpk = (uint32_t*)(ws + 8912896); // 16x256x128 u32
    uint32_t* qpk = (uint32_t*)(ws + 9437184); // 2048x2048 u32

    bn_partial_k<<<64, 256, 0, stream>>>(x, psum, psq);
    bn_final_k<<<4, 256, 0, stream>>>(psum, psq, gamma, beta, scale, shift);

    // merged cvt: x (normalized) | w_q | keys, one launch
    cvt_all_k<<<4608, 256, 0, stream>>>(x, w_q, keys, xpk, wpk, kpk, scale, shift);

    // q = xn @ w_q^T  (writes packed f16-pair q)
    mgemm_k<0><<<dim3(16, 16, 1), 512, 0, stream>>>(xpk, wpk, nullptr, qpk);
    // sim = q @ keys^T  per (p,h)  (fp32 out, overlays dead xpk/wpk)
    mgemm_k<1><<<dim3(16, 2, 16), 512, 0, stream>>>(qpk, kpk, sim, nullptr);

    topk_k<<<2048, 512, 0, stream>>>(sim, eidx, gates);
    expert_k<<<2048, 512, 0, stream>>>(x, down, up, eidx, gates, out);
}